// Round 1
// baseline (148.589 us; speedup 1.0000x reference)
//
#include <hip/hip_runtime.h>
#include <math.h>

// DSA sparse attention, MI355X
// B=2 H=8 S=2048 D=64 VD=64 T=128, fp32 in/out, int32 indices (harness converts).
// One wave (64 lanes) per query (b,h,s); 4 waves/block; blockIdx%16 = plane=(b*H+h)
// so blockIdx%8 keeps each K/V plane (1 MB) on one XCD's L2.

#define BB 2
#define HH 8
#define SS 2048
#define DD 64
#define VDD 64
#define TT 128
#define SCALE 0.125f

__global__ __launch_bounds__(256, 4) void dsa_sparse_attn(
    const float* __restrict__ q,
    const float* __restrict__ k,
    const float* __restrict__ v,
    const int* __restrict__ topk_idx,
    const float* __restrict__ topk_sc,
    float* __restrict__ out)
{
    const int tid  = threadIdx.x;
    const int wave = tid >> 6;
    const int lane = tid & 63;

    const int plane = blockIdx.x & 15;       // b*H + h
    const int s4    = blockIdx.x >> 4;       // 0..511
    const int s     = s4 * 4 + wave;         // 0..2047
    const int b     = plane >> 3;

    const float* qp  = q + ((size_t)plane * SS + s) * DD;
    const float* kp  = k + (size_t)plane * SS * DD;
    const float* vp  = v + (size_t)plane * SS * VDD;
    const int*   ip  = topk_idx + ((size_t)b * SS + s) * TT;
    const float* scp = topk_sc  + ((size_t)b * SS + s) * TT;
    float*       op  = out + ((size_t)plane * SS + s) * VDD;

    // ---- preload indices + indexer scores (2 per lane), park indices in LDS ----
    __shared__ int   s_idx[4][TT];
    __shared__ float s_w[4][TT];

    int   i0  = ip[lane];
    int   i1  = ip[64 + lane];
    float sc0 = scp[lane];
    float sc1 = scp[64 + lane];
    s_idx[wave][lane]      = i0;
    s_idx[wave][64 + lane] = i1;

    // q fragment for the 4-lane-per-row pattern: lane covers d = l*4+16j, j=0..3
    const int l = lane & 3;
    const int g = lane >> 2;
    float4 qf[4];
    #pragma unroll
    for (int j = 0; j < 4; ++j)
        qf[j] = *(const float4*)(qp + l * 4 + 16 * j);

    __syncthreads();

    // ---- phase 1: scores[t] = scale * q . k[idx_t]  (16 rows in flight/wave) ----
    #pragma unroll
    for (int tc = 0; tc < 8; ++tc) {
        int t   = tc * 16 + g;
        int idx = s_idx[wave][t];                    // 16 distinct addrs, bcast x4
        const float* krow = kp + (size_t)idx * DD;
        float acc = 0.f;
        #pragma unroll
        for (int j = 0; j < 4; ++j) {
            float4 kf = *(const float4*)(krow + l * 4 + 16 * j);  // 64B contig/group
            acc += qf[j].x * kf.x + qf[j].y * kf.y + qf[j].z * kf.z + qf[j].w * kf.w;
        }
        acc += __shfl_xor(acc, 1);
        acc += __shfl_xor(acc, 2);
        if (l == 0) s_w[wave][t] = acc * SCALE;
    }
    __syncthreads();

    // ---- phase 2: softmax * topk_score, renormalize (wave-wide) ----
    float a0 = s_w[wave][lane];
    float a1 = s_w[wave][64 + lane];
    float m = fmaxf(a0, a1);
    #pragma unroll
    for (int off = 32; off >= 1; off >>= 1)
        m = fmaxf(m, __shfl_xor(m, off));
    float e0 = __expf(a0 - m) * sc0;
    float e1 = __expf(a1 - m) * sc1;
    float sum = e0 + e1;
    #pragma unroll
    for (int off = 32; off >= 1; off >>= 1)
        sum += __shfl_xor(sum, off);
    float inv = 1.0f / (sum + 1e-12f);
    s_w[wave][lane]      = e0 * inv;
    s_w[wave][64 + lane] = e1 * inv;
    __syncthreads();

    // ---- phase 3: out[d] = sum_t w_t * v[idx_t][d]  (fully coalesced rows) ----
    float acc = 0.f;
    #pragma unroll 8
    for (int t = 0; t < TT; ++t) {
        int   idx = s_idx[wave][t];     // broadcast
        float w   = s_w[wave][t];       // broadcast
        acc = fmaf(w, vp[(size_t)idx * VDD + lane], acc);
    }
    op[lane] = acc;
}

extern "C" void kernel_launch(void* const* d_in, const int* in_sizes, int n_in,
                              void* d_out, int out_size, void* d_ws, size_t ws_size,
                              hipStream_t stream) {
    const float* q   = (const float*)d_in[0];
    const float* k   = (const float*)d_in[1];
    const float* v   = (const float*)d_in[2];
    const int*   idx = (const int*)d_in[3];
    const float* sc  = (const float*)d_in[4];
    float*       out = (float*)d_out;

    dim3 grid(BB * SS / 4 * (BB * HH));  // 512 * 16 = 8192
    dim3 block(256);
    hipLaunchKernelGGL(dsa_sparse_attn, dim3(8192), block, 0, stream,
                       q, k, v, idx, sc, out);
}

// Round 2
// 134.026 us; speedup vs baseline: 1.1087x; 1.1087x over previous
//
#include <hip/hip_runtime.h>
#include <math.h>

// DSA sparse attention, MI355X. B=2 H=8 S=2048 D=64 VD=64 T=128.
// fp32 in/out, int32 indices. One wave per query; 4 waves/block;
// blockIdx%16 = plane=(b*H+h) so blockIdx%8 pins each K/V plane to one XCD L2.
//
// R2: K/V pre-converted to bf16 in d_ws -> gather bytes halve (2.1GB->1.05GB,
// L2 floor 60->30us). Phase1: 8 lanes/row, dwordx4/lane (256B/instr).
// Phase3: 2 rows/iter, dword = 2 bf16 dims (64 iters, 256B/instr).

#define BB 2
#define HH 8
#define SS 2048
#define DD 64
#define VDD 64
#define TT 128
#define SCALE 0.125f
#define NKV (BB * HH * SS * DD)          // 2097152 elements each for k and v

__device__ __forceinline__ float bf_lo(unsigned int u) {
    return __uint_as_float(u << 16);
}
__device__ __forceinline__ float bf_hi(unsigned int u) {
    return __uint_as_float(u & 0xFFFF0000u);
}
__device__ __forceinline__ unsigned short f2bf_rne(float f) {
    unsigned int u = __float_as_uint(f);
    u += 0x7FFFu + ((u >> 16) & 1u);     // round-to-nearest-even
    return (unsigned short)(u >> 16);
}

// ---- pre-pass: fp32 k,v -> bf16 kb,vb (packed 2/dword) ----
__global__ __launch_bounds__(256) void cvt_kv_bf16(
    const float* __restrict__ k, const float* __restrict__ v,
    unsigned int* __restrict__ kb, unsigned int* __restrict__ vb)
{
    int i = (blockIdx.x * 256 + threadIdx.x) * 4;   // 4 floats -> 2 dwords
    if (i >= NKV) return;
    float4 kf = *(const float4*)(k + i);
    float4 vf = *(const float4*)(v + i);
    unsigned int k0 = (unsigned int)f2bf_rne(kf.x) | ((unsigned int)f2bf_rne(kf.y) << 16);
    unsigned int k1 = (unsigned int)f2bf_rne(kf.z) | ((unsigned int)f2bf_rne(kf.w) << 16);
    unsigned int v0 = (unsigned int)f2bf_rne(vf.x) | ((unsigned int)f2bf_rne(vf.y) << 16);
    unsigned int v1 = (unsigned int)f2bf_rne(vf.z) | ((unsigned int)f2bf_rne(vf.w) << 16);
    *(uint2*)(kb + i / 2) = make_uint2(k0, k1);
    *(uint2*)(vb + i / 2) = make_uint2(v0, v1);
}

// ---- main: bf16 gather path ----
__global__ __launch_bounds__(256, 4) void dsa_sparse_attn_bf16(
    const float* __restrict__ q,
    const unsigned int* __restrict__ kb,   // bf16 pairs, row = 32 dwords
    const unsigned int* __restrict__ vb,
    const int* __restrict__ topk_idx,
    const float* __restrict__ topk_sc,
    float* __restrict__ out)
{
    const int tid  = threadIdx.x;
    const int wave = tid >> 6;
    const int lane = tid & 63;

    const int plane = blockIdx.x & 15;
    const int s4    = blockIdx.x >> 4;
    const int s     = s4 * 4 + wave;
    const int b     = plane >> 3;

    const float*        qp  = q  + ((size_t)plane * SS + s) * DD;
    const unsigned int* kp  = kb + (size_t)plane * SS * (DD / 2);
    const unsigned int* vp  = vb + (size_t)plane * SS * (VDD / 2);
    const int*          ip  = topk_idx + ((size_t)b * SS + s) * TT;
    const float*        scp = topk_sc  + ((size_t)b * SS + s) * TT;
    float*              op  = out + ((size_t)plane * SS + s) * VDD;

    __shared__ int   s_idx[4][TT];
    __shared__ float s_w[4][TT];

    int   i0  = ip[lane];
    int   i1  = ip[64 + lane];
    float sc0 = scp[lane];
    float sc1 = scp[64 + lane];
    s_idx[wave][lane]      = i0;
    s_idx[wave][64 + lane] = i1;

    // phase1 layout: 8 lanes per row; lane covers d = h*8 .. h*8+7
    const int h = lane & 7;
    const int g = lane >> 3;
    float qf[8];
    {
        float4 qa = *(const float4*)(qp + h * 8);
        float4 qb = *(const float4*)(qp + h * 8 + 4);
        qf[0] = qa.x; qf[1] = qa.y; qf[2] = qa.z; qf[3] = qa.w;
        qf[4] = qb.x; qf[5] = qb.y; qf[6] = qb.z; qf[7] = qb.w;
    }

    __syncthreads();

    // ---- phase 1: scores[t] = scale * q . k[idx_t]; 8 rows in flight/wave ----
    #pragma unroll
    for (int tc = 0; tc < 16; ++tc) {
        int t   = tc * 8 + g;
        int idx = s_idx[wave][t];
        uint4 kk = *(const uint4*)(kp + (size_t)idx * 32 + h * 4);  // 16B/lane, 128B/row
        float acc;
        acc  = qf[0] * bf_lo(kk.x) + qf[1] * bf_hi(kk.x);
        acc += qf[2] * bf_lo(kk.y) + qf[3] * bf_hi(kk.y);
        acc += qf[4] * bf_lo(kk.z) + qf[5] * bf_hi(kk.z);
        acc += qf[6] * bf_lo(kk.w) + qf[7] * bf_hi(kk.w);
        acc += __shfl_xor(acc, 1);
        acc += __shfl_xor(acc, 2);
        acc += __shfl_xor(acc, 4);
        if (h == 0) s_w[wave][t] = acc * SCALE;
    }
    __syncthreads();

    // ---- phase 2: softmax * topk_score, renormalize ----
    float a0 = s_w[wave][lane];
    float a1 = s_w[wave][64 + lane];
    float m = fmaxf(a0, a1);
    #pragma unroll
    for (int off = 32; off >= 1; off >>= 1)
        m = fmaxf(m, __shfl_xor(m, off));
    float e0 = __expf(a0 - m) * sc0;
    float e1 = __expf(a1 - m) * sc1;
    float sum = e0 + e1;
    #pragma unroll
    for (int off = 32; off >= 1; off >>= 1)
        sum += __shfl_xor(sum, off);
    float inv = 1.0f / (sum + 1e-12f);
    s_w[wave][lane]      = e0 * inv;
    s_w[wave][64 + lane] = e1 * inv;
    __syncthreads();

    // ---- phase 3: 2 rows/iter; lanes 0-31 row t, lanes 32-63 row t+1 ----
    const int half = lane >> 5;
    const int li   = lane & 31;          // dword index within row: dims 2li, 2li+1
    float ax = 0.f, ay = 0.f;
    #pragma unroll 8
    for (int tc = 0; tc < 64; ++tc) {
        int   t   = tc * 2 + half;
        int   idx = s_idx[wave][t];
        float w   = s_w[wave][t];
        unsigned int u = vp[(size_t)idx * 32 + li];
        ax = fmaf(w, bf_lo(u), ax);
        ay = fmaf(w, bf_hi(u), ay);
    }
    ax += __shfl_xor(ax, 32);
    ay += __shfl_xor(ay, 32);
    if (half == 0)
        *(float2*)(op + li * 2) = make_float2(ax, ay);
}

// ---- fallback fp32 kernel (used if ws too small) ----
__global__ __launch_bounds__(256, 4) void dsa_sparse_attn_f32(
    const float* __restrict__ q,
    const float* __restrict__ k,
    const float* __restrict__ v,
    const int* __restrict__ topk_idx,
    const float* __restrict__ topk_sc,
    float* __restrict__ out)
{
    const int tid  = threadIdx.x;
    const int wave = tid >> 6;
    const int lane = tid & 63;
    const int plane = blockIdx.x & 15;
    const int s     = (blockIdx.x >> 4) * 4 + wave;
    const int b     = plane >> 3;

    const float* qp  = q + ((size_t)plane * SS + s) * DD;
    const float* kp  = k + (size_t)plane * SS * DD;
    const float* vp  = v + (size_t)plane * SS * VDD;
    const int*   ip  = topk_idx + ((size_t)b * SS + s) * TT;
    const float* scp = topk_sc  + ((size_t)b * SS + s) * TT;
    float*       op  = out + ((size_t)plane * SS + s) * VDD;

    __shared__ int   s_idx[4][TT];
    __shared__ float s_w[4][TT];

    float sc0 = scp[lane];
    float sc1 = scp[64 + lane];
    s_idx[wave][lane]      = ip[lane];
    s_idx[wave][64 + lane] = ip[64 + lane];

    const int l = lane & 3;
    const int g = lane >> 2;
    float4 qf[4];
    #pragma unroll
    for (int j = 0; j < 4; ++j) qf[j] = *(const float4*)(qp + l * 4 + 16 * j);
    __syncthreads();

    #pragma unroll
    for (int tc = 0; tc < 8; ++tc) {
        int t = tc * 16 + g;
        const float* krow = kp + (size_t)s_idx[wave][t] * DD;
        float acc = 0.f;
        #pragma unroll
        for (int j = 0; j < 4; ++j) {
            float4 kf = *(const float4*)(krow + l * 4 + 16 * j);
            acc += qf[j].x * kf.x + qf[j].y * kf.y + qf[j].z * kf.z + qf[j].w * kf.w;
        }
        acc += __shfl_xor(acc, 1);
        acc += __shfl_xor(acc, 2);
        if (l == 0) s_w[wave][t] = acc * SCALE;
    }
    __syncthreads();

    float a0 = s_w[wave][lane];
    float a1 = s_w[wave][64 + lane];
    float m = fmaxf(a0, a1);
    #pragma unroll
    for (int off = 32; off >= 1; off >>= 1) m = fmaxf(m, __shfl_xor(m, off));
    float e0 = __expf(a0 - m) * sc0;
    float e1 = __expf(a1 - m) * sc1;
    float sum = e0 + e1;
    #pragma unroll
    for (int off = 32; off >= 1; off >>= 1) sum += __shfl_xor(sum, off);
    float inv = 1.0f / (sum + 1e-12f);
    s_w[wave][lane]      = e0 * inv;
    s_w[wave][64 + lane] = e1 * inv;
    __syncthreads();

    float acc = 0.f;
    #pragma unroll 8
    for (int t = 0; t < TT; ++t)
        acc = fmaf(s_w[wave][t], vp[(size_t)s_idx[wave][t] * VDD + lane], acc);
    op[lane] = acc;
}

extern "C" void kernel_launch(void* const* d_in, const int* in_sizes, int n_in,
                              void* d_out, int out_size, void* d_ws, size_t ws_size,
                              hipStream_t stream) {
    const float* q   = (const float*)d_in[0];
    const float* k   = (const float*)d_in[1];
    const float* v   = (const float*)d_in[2];
    const int*   idx = (const int*)d_in[3];
    const float* sc  = (const float*)d_in[4];
    float*       out = (float*)d_out;

    const size_t need = (size_t)NKV * 2 * 2;   // kb + vb, 2B each = 8.4 MB
    if (ws_size >= need) {
        unsigned int* kb = (unsigned int*)d_ws;
        unsigned int* vb = kb + NKV / 2;
        hipLaunchKernelGGL(cvt_kv_bf16, dim3(NKV / 4 / 256), dim3(256), 0, stream,
                           k, v, kb, vb);
        hipLaunchKernelGGL(dsa_sparse_attn_bf16, dim3(8192), dim3(256), 0, stream,
                           q, kb, vb, idx, sc, out);
    } else {
        hipLaunchKernelGGL(dsa_sparse_attn_f32, dim3(8192), dim3(256), 0, stream,
                           q, k, v, idx, sc, out);
    }
}

// Round 3
// 130.716 us; speedup vs baseline: 1.1367x; 1.0253x over previous
//
#include <hip/hip_runtime.h>
#include <math.h>

// DSA sparse attention, MI355X. B=2 H=8 S=2048 D=64 VD=64 T=128.
// fp32 in/out, int32 indices. One wave per query; 4 waves/block;
// blockIdx%16 = plane=(b*H+h) so blockIdx%8 pins each K/V plane to one XCD L2.
//
// R3 (VALU-bound per R2 counters: VALUBusy 80%, HBM 5%):
//  - bf16 hi-half unpack via direct reinterpret (junk low mantissa bits are
//    below bf16 rounding noise) -> kills all v_and ops.
//  - phase 3: dwordx4/lane, 8 lanes/row, 16 iters (was 64 x dword), 8 fp32
//    accumulators/lane, shfl-reduce over row-groups at the end.
//  - (weight,idx) packed as uint2 in LDS; phase 3 preloads them with 16
//    ds_read_b64 instead of 128 per-iter ds_read_b32.

#define BB 2
#define HH 8
#define SS 2048
#define DD 64
#define VDD 64
#define TT 128
#define SCALE 0.125f
#define NKV (BB * HH * SS * DD)          // 2097152 elements each for k and v

__device__ __forceinline__ float bf_lo(unsigned int u) {
    return __uint_as_float(u << 16);
}
// hi bf16 WITHOUT masking: low 16 junk bits perturb mantissa below bf16
// rounding noise (<= 2^-7 ulp-relative). Saves one v_and per dword.
__device__ __forceinline__ float bf_hi(unsigned int u) {
    return __uint_as_float(u);
}
__device__ __forceinline__ unsigned short f2bf_rne(float f) {
    unsigned int u = __float_as_uint(f);
    u += 0x7FFFu + ((u >> 16) & 1u);     // round-to-nearest-even
    return (unsigned short)(u >> 16);
}

// ---- pre-pass: fp32 k,v -> bf16 kb,vb (packed 2/dword) ----
__global__ __launch_bounds__(256) void cvt_kv_bf16(
    const float* __restrict__ k, const float* __restrict__ v,
    unsigned int* __restrict__ kb, unsigned int* __restrict__ vb)
{
    int i = (blockIdx.x * 256 + threadIdx.x) * 4;   // 4 floats -> 2 dwords
    if (i >= NKV) return;
    float4 kf = *(const float4*)(k + i);
    float4 vf = *(const float4*)(v + i);
    unsigned int k0 = (unsigned int)f2bf_rne(kf.x) | ((unsigned int)f2bf_rne(kf.y) << 16);
    unsigned int k1 = (unsigned int)f2bf_rne(kf.z) | ((unsigned int)f2bf_rne(kf.w) << 16);
    unsigned int v0 = (unsigned int)f2bf_rne(vf.x) | ((unsigned int)f2bf_rne(vf.y) << 16);
    unsigned int v1 = (unsigned int)f2bf_rne(vf.z) | ((unsigned int)f2bf_rne(vf.w) << 16);
    *(uint2*)(kb + i / 2) = make_uint2(k0, k1);
    *(uint2*)(vb + i / 2) = make_uint2(v0, v1);
}

// ---- main: bf16 gather path ----
__global__ __launch_bounds__(256, 4) void dsa_sparse_attn_bf16(
    const float* __restrict__ q,
    const unsigned int* __restrict__ kb,   // bf16 pairs, row = 32 dwords
    const unsigned int* __restrict__ vb,
    const int* __restrict__ topk_idx,
    const float* __restrict__ topk_sc,
    float* __restrict__ out)
{
    const int tid  = threadIdx.x;
    const int wave = tid >> 6;
    const int lane = tid & 63;
    const int h    = lane & 7;           // dim-group: dwords h*4..h*4+3 (dims h*8..h*8+7)
    const int g    = lane >> 3;          // row-group: rows t = i*8+g

    const int plane = blockIdx.x & 15;
    const int s     = (blockIdx.x >> 4) * 4 + wave;
    const int b     = plane >> 3;

    const float*        qp  = q  + ((size_t)plane * SS + s) * DD;
    const unsigned int* kp  = kb + (size_t)plane * SS * (DD / 2);
    const unsigned int* vp  = vb + (size_t)plane * SS * (VDD / 2);
    const int*          ip  = topk_idx + ((size_t)b * SS + s) * TT;
    const float*        scp = topk_sc  + ((size_t)b * SS + s) * TT;
    float*              op  = out + ((size_t)plane * SS + s) * VDD;

    // .x = score -> normalized weight bits, .y = gather index
    __shared__ uint2 s_wi[4][TT];

    float sc0 = scp[lane];
    float sc1 = scp[64 + lane];
    s_wi[wave][lane].y      = (unsigned int)ip[lane];
    s_wi[wave][64 + lane].y = (unsigned int)ip[64 + lane];

    // q fragment: dims h*8 .. h*8+7
    float4 qa = *(const float4*)(qp + h * 8);
    float4 qb = *(const float4*)(qp + h * 8 + 4);

    __syncthreads();

    // ---- phase 1: scores[t] = scale * q . k[idx_t]; 8 rows in flight/wave ----
    #pragma unroll
    for (int tc = 0; tc < 16; ++tc) {
        int t   = tc * 8 + g;
        int idx = (int)s_wi[wave][t].y;
        uint4 kk = *(const uint4*)(kp + (size_t)idx * 32 + h * 4);  // 16B/lane, 128B/row
        float acc;
        acc  = qa.x * bf_lo(kk.x) + qa.y * bf_hi(kk.x);
        acc += qa.z * bf_lo(kk.y) + qa.w * bf_hi(kk.y);
        acc += qb.x * bf_lo(kk.z) + qb.y * bf_hi(kk.z);
        acc += qb.z * bf_lo(kk.w) + qb.w * bf_hi(kk.w);
        acc += __shfl_xor(acc, 1);
        acc += __shfl_xor(acc, 2);
        acc += __shfl_xor(acc, 4);
        if (h == 0) s_wi[wave][t].x = __float_as_uint(acc * SCALE);
    }
    __syncthreads();

    // ---- phase 2: softmax * topk_score, renormalize ----
    float a0 = __uint_as_float(s_wi[wave][lane].x);
    float a1 = __uint_as_float(s_wi[wave][64 + lane].x);
    float m = fmaxf(a0, a1);
    #pragma unroll
    for (int off = 32; off >= 1; off >>= 1)
        m = fmaxf(m, __shfl_xor(m, off));
    float e0 = __expf(a0 - m) * sc0;
    float e1 = __expf(a1 - m) * sc1;
    float sum = e0 + e1;
    #pragma unroll
    for (int off = 32; off >= 1; off >>= 1)
        sum += __shfl_xor(sum, off);
    float inv = 1.0f / (sum + 1e-12f);
    s_wi[wave][lane].x      = __float_as_uint(e0 * inv);
    s_wi[wave][64 + lane].x = __float_as_uint(e1 * inv);
    __syncthreads();

    // ---- phase 3: out[d] = sum_t w_t * v[idx_t][d]; 8 rows/iter, dwordx4 ----
    float a[8] = {0.f, 0.f, 0.f, 0.f, 0.f, 0.f, 0.f, 0.f};
    #pragma unroll
    for (int i = 0; i < 16; ++i) {
        uint2 wi = s_wi[wave][i * 8 + g];          // ds_read_b64, broadcast in group
        float w  = __uint_as_float(wi.x);
        int  idx = (int)wi.y;
        uint4 u = *(const uint4*)(vp + (size_t)idx * 32 + h * 4);
        a[0] = fmaf(w, bf_lo(u.x), a[0]);  a[1] = fmaf(w, bf_hi(u.x), a[1]);
        a[2] = fmaf(w, bf_lo(u.y), a[2]);  a[3] = fmaf(w, bf_hi(u.y), a[3]);
        a[4] = fmaf(w, bf_lo(u.z), a[4]);  a[5] = fmaf(w, bf_hi(u.z), a[5]);
        a[6] = fmaf(w, bf_lo(u.w), a[6]);  a[7] = fmaf(w, bf_hi(u.w), a[7]);
    }
    // reduce over the 8 row-groups (lane bits 3..5)
    #pragma unroll
    for (int j = 0; j < 8; ++j) {
        a[j] += __shfl_xor(a[j], 8);
        a[j] += __shfl_xor(a[j], 16);
        a[j] += __shfl_xor(a[j], 32);
    }
    if (g == 0) {
        *(float4*)(op + h * 8)     = make_float4(a[0], a[1], a[2], a[3]);
        *(float4*)(op + h * 8 + 4) = make_float4(a[4], a[5], a[6], a[7]);
    }
}

// ---- fallback fp32 kernel (used if ws too small) ----
__global__ __launch_bounds__(256, 4) void dsa_sparse_attn_f32(
    const float* __restrict__ q,
    const float* __restrict__ k,
    const float* __restrict__ v,
    const int* __restrict__ topk_idx,
    const float* __restrict__ topk_sc,
    float* __restrict__ out)
{
    const int tid  = threadIdx.x;
    const int wave = tid >> 6;
    const int lane = tid & 63;
    const int plane = blockIdx.x & 15;
    const int s     = (blockIdx.x >> 4) * 4 + wave;
    const int b     = plane >> 3;

    const float* qp  = q + ((size_t)plane * SS + s) * DD;
    const float* kp  = k + (size_t)plane * SS * DD;
    const float* vp  = v + (size_t)plane * SS * VDD;
    const int*   ip  = topk_idx + ((size_t)b * SS + s) * TT;
    const float* scp = topk_sc  + ((size_t)b * SS + s) * TT;
    float*       op  = out + ((size_t)plane * SS + s) * VDD;

    __shared__ int   s_idx[4][TT];
    __shared__ float s_w[4][TT];

    float sc0 = scp[lane];
    float sc1 = scp[64 + lane];
    s_idx[wave][lane]      = ip[lane];
    s_idx[wave][64 + lane] = ip[64 + lane];

    const int l = lane & 3;
    const int g = lane >> 2;
    float4 qf[4];
    #pragma unroll
    for (int j = 0; j < 4; ++j) qf[j] = *(const float4*)(qp + l * 4 + 16 * j);
    __syncthreads();

    #pragma unroll
    for (int tc = 0; tc < 8; ++tc) {
        int t = tc * 16 + g;
        const float* krow = kp + (size_t)s_idx[wave][t] * DD;
        float acc = 0.f;
        #pragma unroll
        for (int j = 0; j < 4; ++j) {
            float4 kf = *(const float4*)(krow + l * 4 + 16 * j);
            acc += qf[j].x * kf.x + qf[j].y * kf.y + qf[j].z * kf.z + qf[j].w * kf.w;
        }
        acc += __shfl_xor(acc, 1);
        acc += __shfl_xor(acc, 2);
        if (l == 0) s_w[wave][t] = acc * SCALE;
    }
    __syncthreads();

    float a0 = s_w[wave][lane];
    float a1 = s_w[wave][64 + lane];
    float m = fmaxf(a0, a1);
    #pragma unroll
    for (int off = 32; off >= 1; off >>= 1) m = fmaxf(m, __shfl_xor(m, off));
    float e0 = __expf(a0 - m) * sc0;
    float e1 = __expf(a1 - m) * sc1;
    float sum = e0 + e1;
    #pragma unroll
    for (int off = 32; off >= 1; off >>= 1) sum += __shfl_xor(sum, off);
    float inv = 1.0f / (sum + 1e-12f);
    s_w[wave][lane]      = e0 * inv;
    s_w[wave][64 + lane] = e1 * inv;
    __syncthreads();

    float acc = 0.f;
    #pragma unroll 8
    for (int t = 0; t < TT; ++t)
        acc = fmaf(s_w[wave][t], vp[(size_t)s_idx[wave][t] * VDD + lane], acc);
    op[lane] = acc;
}

extern "C" void kernel_launch(void* const* d_in, const int* in_sizes, int n_in,
                              void* d_out, int out_size, void* d_ws, size_t ws_size,
                              hipStream_t stream) {
    const float* q   = (const float*)d_in[0];
    const float* k   = (const float*)d_in[1];
    const float* v   = (const float*)d_in[2];
    const int*   idx = (const int*)d_in[3];
    const float* sc  = (const float*)d_in[4];
    float*       out = (float*)d_out;

    const size_t need = (size_t)NKV * 2 * 2;   // kb + vb, 2B each = 8.4 MB
    if (ws_size >= need) {
        unsigned int* kb = (unsigned int*)d_ws;
        unsigned int* vb = kb + NKV / 2;
        hipLaunchKernelGGL(cvt_kv_bf16, dim3(NKV / 4 / 256), dim3(256), 0, stream,
                           k, v, kb, vb);
        hipLaunchKernelGGL(dsa_sparse_attn_bf16, dim3(8192), dim3(256), 0, stream,
                           q, kb, vb, idx, sc, out);
    } else {
        hipLaunchKernelGGL(dsa_sparse_attn_f32, dim3(8192), dim3(256), 0, stream,
                           q, k, v, idx, sc, out);
    }
}